// Round 15
// baseline (82.064 us; speedup 1.0000x reference)
//
#include <hip/hip_runtime.h>
#include <hip/hip_bf16.h>

#define B_SZ  128
#define CH    64
#define T_LEN 4096
#define HID   32
#define INS   3

typedef __attribute__((ext_vector_type(8))) short short8;   // 8 bf16 (4 VGPRs)
typedef __attribute__((ext_vector_type(4))) float f32x4;
typedef __attribute__((address_space(1))) const float gfloat1;
typedef __attribute__((address_space(3))) float sfloat3;

__device__ inline unsigned short f2bf_bits(float f) {
  __hip_bfloat16 h = __float2bfloat16(f);
  union { __hip_bfloat16 h; unsigned short u; } cv;
  cv.h = h;
  return cv.u;
}

// ---------------------------------------------------------------------------
// Kernel 1: hypernetwork MLPs. One block per batch sample.
// Emits weight as bf16 in natural [b][o][i] order + fp32 bias.
// ---------------------------------------------------------------------------
__global__ __launch_bounds__(256) void hyper_mlp_kernel(
    const float* __restrict__ z,
    const float* __restrict__ w_w1, const float* __restrict__ w_b1,
    const float* __restrict__ w_g,  const float* __restrict__ w_beta,
    const float* __restrict__ w_w2, const float* __restrict__ w_b2,
    const float* __restrict__ b_w1, const float* __restrict__ b_b1,
    const float* __restrict__ b_g,  const float* __restrict__ b_beta,
    const float* __restrict__ b_w2, const float* __restrict__ b_b2,
    unsigned short* __restrict__ wbf,  // [B][CH_out][CH_in] bf16 bits
    float* __restrict__ bias)          // [B][CH]
{
  const int b   = blockIdx.x;
  const int tid = threadIdx.x;

  __shared__ float zs[INS];
  __shared__ float hraw[2][HID];
  __shared__ float hn[2][HID];

  if (tid < INS) zs[tid] = z[b * INS + tid];
  __syncthreads();

  if (tid < 2 * HID) {
    const int grp = tid >> 5;          // 0 = weight-MLP, 1 = bias-MLP
    const int j   = tid & 31;
    const float* w1 = grp ? b_w1 : w_w1;
    const float* b1 = grp ? b_b1 : w_b1;
    hraw[grp][j] = w1[j*3+0]*zs[0] + w1[j*3+1]*zs[1] + w1[j*3+2]*zs[2] + b1[j];
  }
  __syncthreads();

  if (tid < 2 * HID) {
    const int grp = tid >> 5;
    const int j   = tid & 31;
    float mu = 0.f;
    #pragma unroll
    for (int k = 0; k < HID; ++k) mu += hraw[grp][k];
    mu *= (1.0f / HID);
    float var = 0.f;
    #pragma unroll
    for (int k = 0; k < HID; ++k) { float d = hraw[grp][k] - mu; var += d * d; }
    var *= (1.0f / HID);
    const float r  = rsqrtf(var + 1e-5f);
    const float* g  = grp ? b_g    : w_g;
    const float* be = grp ? b_beta : w_beta;
    const float v = (hraw[grp][j] - mu) * r * g[j] + be[j];
    hn[grp][j] = fmaxf(v, 0.f);
  }
  __syncthreads();

  for (int m = tid; m < CH * CH; m += 256) {
    const float* row = w_w2 + m * HID;
    float acc = w_b2[m];
    #pragma unroll
    for (int i = 0; i < HID; ++i) acc += hn[0][i] * row[i];
    wbf[(size_t)b * CH * CH + m] = f2bf_bits(acc);
  }

  if (tid < CH) {
    const float* row = b_w2 + tid * HID;
    float acc = b_b2[tid];
    #pragma unroll
    for (int i = 0; i < HID; ++i) acc += hn[1][i] * row[i];
    bias[b * CH + tid] = acc;
  }
}

// ---------------------------------------------------------------------------
// Kernel 2: out[b] = W[b] (64x64) @ x[b] (64x4096) + bias via bf16 MFMA.
// Round-15 change: ZERO BARRIERS -- fully wave-private pipelines.
// Every prior variant (r10-r14, all 66-72us) coupled 4 waves with s_barrier
// per phase: each phase advances at the MAX of 4 load tails and resident
// blocks quantize into lockstep burst/drain. A copy kernel (6.3 TB/s) has no
// inter-wave coupling. Here each wave owns whole (b, 64-t) windows: stages
// all 64 k-rows into its PRIVATE 2-slot LDS (same proven 260-pitch layout),
// consumes them itself. Block = 2 waves, LDS 66560 B -> 2 blocks/CU, grid
// 512 = exactly 2/CU, 8 windows/wave fully unrolled.
// Per-wave vmcnt ledger (uniform): phase p waits vmcnt(16) = keep exactly
// the 16-inst prefetch L_{p+1}, retire L_p + all older stores. Slot restage
// is safe: ds_reads are lgkm-retired (data in VGPRs) before the restage
// issues, and vmcnt in-order retirement guarantees the ledger.
// ---------------------------------------------------------------------------
#define STAGEW(SLOT, J)                                                       \
  {                                                                           \
    _Pragma("unroll")                                                         \
    for (int m = 0; m < 16; ++m) {                                            \
      const float* ga = xb + (size_t)(4 * m + rowin) * T_LEN                  \
                           + (wid + 2 * (J)) * 64 + col4;                     \
      __builtin_amdgcn_global_load_lds((gfloat1*)ga,                          \
          (sfloat3*)(lds + (wid * 2 + (SLOT)) * 4160 + m * 260), 16, 0, 0);   \
    }                                                                         \
  }

#define COMPW(SLOT, J)                                                        \
  {                                                                           \
    const int wt = (wid + 2 * (J)) * 64;                                      \
    _Pragma("unroll")                                                         \
    for (int nt = 0; nt < 4; ++nt) {                                          \
      f32x4 a0 = {bv[0][0], bv[0][1], bv[0][2], bv[0][3]};                    \
      f32x4 a1 = {bv[1][0], bv[1][1], bv[1][2], bv[1][3]};                    \
      f32x4 a2 = {bv[2][0], bv[2][1], bv[2][2], bv[2][3]};                    \
      f32x4 a3 = {bv[3][0], bv[3][1], bv[3][2], bv[3][3]};                    \
      _Pragma("unroll")                                                       \
      for (int ks = 0; ks < 2; ++ks) {                                        \
        union { short8 s; unsigned short u[8]; } bfv;                         \
        _Pragma("unroll")                                                     \
        for (int j = 0; j < 8; ++j) {                                         \
          const float f = lds[(wid * 2 + (SLOT)) * 4160                       \
                              + (ks * 8 + g * 2 + (j >> 2)) * 260            \
                              + (j & 3) * 64 + nt * 16 + r];                  \
          bfv.u[j] = f2bf_bits(f);                                            \
        }                                                                     \
        a0 = __builtin_amdgcn_mfma_f32_16x16x32_bf16(afrag[0][ks], bfv.s, a0, 0, 0, 0); \
        a1 = __builtin_amdgcn_mfma_f32_16x16x32_bf16(afrag[1][ks], bfv.s, a1, 0, 0, 0); \
        a2 = __builtin_amdgcn_mfma_f32_16x16x32_bf16(afrag[2][ks], bfv.s, a2, 0, 0, 0); \
        a3 = __builtin_amdgcn_mfma_f32_16x16x32_bf16(afrag[3][ks], bfv.s, a3, 0, 0, 0); \
      }                                                                       \
      float* os = ob + wt + nt * 16 + r;                                      \
      _Pragma("unroll")                                                       \
      for (int q = 0; q < 4; ++q) {                                           \
        os[(size_t)(0 * 16 + g * 4 + q) * T_LEN] = a0[q];                     \
        os[(size_t)(1 * 16 + g * 4 + q) * T_LEN] = a1[q];                     \
        os[(size_t)(2 * 16 + g * 4 + q) * T_LEN] = a2[q];                     \
        os[(size_t)(3 * 16 + g * 4 + q) * T_LEN] = a3[q];                     \
      }                                                                       \
    }                                                                         \
  }

#define WAITV                                                                 \
  { asm volatile("s_waitcnt vmcnt(16)" ::: "memory"); }

__global__ __launch_bounds__(128, 2) void conv1x1_mfma(
    const float* __restrict__ x,
    const unsigned short* __restrict__ wbf,
    const float* __restrict__ bias,
    float* __restrict__ out)
{
  __shared__ __align__(16) float lds[4 * 4160];   // 66560 B: 2 waves x 2 slots

  const int b     = blockIdx.y;
  const int tbi   = blockIdx.x;     // 1024-t quarter (0..3)
  const int tid   = threadIdx.x;
  const int lane  = tid & 63;
  const int wid   = tid >> 6;       // 0..1 (uniform per wave)
  const int g     = lane >> 4;      // 16-lane group
  const int r     = lane & 15;
  const int rowin = lane >> 4;      // staging row-in-group
  const int col4  = (lane & 15) * 4;

  // A-frags: wbf[b][ot*16 + r][ks*32 + g*8 + 0..7]  (8 x 16B loads)
  const unsigned short* wb = wbf + (size_t)b * CH * CH;
  short8 afrag[4][2];
  #pragma unroll
  for (int ot = 0; ot < 4; ++ot)
    #pragma unroll
    for (int ks = 0; ks < 2; ++ks)
      afrag[ot][ks] = *(const short8*)(wb + (ot * 16 + r) * CH + ks * 32 + g * 8);

  // bias for lane's output rows o = ot*16 + g*4 + q  (4 x 16B loads)
  float bv[4][4];
  #pragma unroll
  for (int ot = 0; ot < 4; ++ot) {
    const float4 t = *(const float4*)(bias + b * CH + ot * 16 + g * 4);
    bv[ot][0] = t.x; bv[ot][1] = t.y; bv[ot][2] = t.z; bv[ot][3] = t.w;
  }

  const float* xb = x   + (size_t)b * CH * T_LEN + tbi * 1024;
  float*       ob = out + (size_t)b * CH * T_LEN + tbi * 1024;

  STAGEW(0, 0)
  STAGEW(1, 1)

  WAITV  COMPW(0, 0)  STAGEW(0, 2)
  WAITV  COMPW(1, 1)  STAGEW(1, 3)
  WAITV  COMPW(0, 2)  STAGEW(0, 4)
  WAITV  COMPW(1, 3)  STAGEW(1, 5)
  WAITV  COMPW(0, 4)  STAGEW(0, 6)
  WAITV  COMPW(1, 5)  STAGEW(1, 7)
  WAITV  COMPW(0, 6)
  WAITV  COMPW(1, 7)
}

extern "C" void kernel_launch(void* const* d_in, const int* in_sizes, int n_in,
                              void* d_out, int out_size, void* d_ws, size_t ws_size,
                              hipStream_t stream) {
  const float* x      = (const float*)d_in[0];
  const float* z      = (const float*)d_in[1];
  const float* w_w1   = (const float*)d_in[2];
  const float* w_b1   = (const float*)d_in[3];
  const float* w_g    = (const float*)d_in[4];
  const float* w_beta = (const float*)d_in[5];
  const float* w_w2   = (const float*)d_in[6];
  const float* w_b2   = (const float*)d_in[7];
  const float* b_w1   = (const float*)d_in[8];
  const float* b_b1   = (const float*)d_in[9];
  const float* b_g    = (const float*)d_in[10];
  const float* b_beta = (const float*)d_in[11];
  const float* b_w2   = (const float*)d_in[12];
  const float* b_b2   = (const float*)d_in[13];

  float* out = (float*)d_out;
  unsigned short* wbf = (unsigned short*)d_ws;                 // 128*4096 bf16 = 1 MB
  float* bias = (float*)((char*)d_ws + (size_t)B_SZ * CH * CH * sizeof(unsigned short));

  hyper_mlp_kernel<<<B_SZ, 256, 0, stream>>>(
      z, w_w1, w_b1, w_g, w_beta, w_w2, w_b2,
      b_w1, b_b1, b_g, b_beta, b_w2, b_b2, wbf, bias);

  dim3 grid(T_LEN / 1024, B_SZ);
  conv1x1_mfma<<<grid, 128, 0, stream>>>(x, wbf, bias, out);
}

// Round 16
// 66.108 us; speedup vs baseline: 1.2414x; 1.2414x over previous
//
#include <hip/hip_runtime.h>
#include <hip/hip_bf16.h>

#define B_SZ  128
#define CH    64
#define T_LEN 4096
#define HID   32
#define INS   3

#define PITCH  260      // floats per k-row in LDS (256 t + 4 pad)
#define HALF_F 8384     // floats per k-half (32 rows * 260 + 24 offset, 16B-aligned)

typedef __attribute__((ext_vector_type(8))) short short8;   // 8 bf16 (4 VGPRs)
typedef __attribute__((ext_vector_type(4))) float f32x4;
typedef __attribute__((address_space(1))) const float gfloat1;
typedef __attribute__((address_space(3))) float sfloat3;

__device__ inline unsigned short f2bf_bits(float f) {
  __hip_bfloat16 h = __float2bfloat16(f);
  union { __hip_bfloat16 h; unsigned short u; } cv;
  cv.h = h;
  return cv.u;
}

// ---------------------------------------------------------------------------
// Kernel 1: hypernetwork MLPs. One block per batch sample.
// Emits weight as bf16 in natural [b][o][i] order + fp32 bias.
// ---------------------------------------------------------------------------
__global__ __launch_bounds__(256) void hyper_mlp_kernel(
    const float* __restrict__ z,
    const float* __restrict__ w_w1, const float* __restrict__ w_b1,
    const float* __restrict__ w_g,  const float* __restrict__ w_beta,
    const float* __restrict__ w_w2, const float* __restrict__ w_b2,
    const float* __restrict__ b_w1, const float* __restrict__ b_b1,
    const float* __restrict__ b_g,  const float* __restrict__ b_beta,
    const float* __restrict__ b_w2, const float* __restrict__ b_b2,
    unsigned short* __restrict__ wbf,  // [B][CH_out][CH_in] bf16 bits
    float* __restrict__ bias)          // [B][CH]
{
  const int b   = blockIdx.x;
  const int tid = threadIdx.x;

  __shared__ float zs[INS];
  __shared__ float hraw[2][HID];
  __shared__ float hn[2][HID];

  if (tid < INS) zs[tid] = z[b * INS + tid];
  __syncthreads();

  if (tid < 2 * HID) {
    const int grp = tid >> 5;          // 0 = weight-MLP, 1 = bias-MLP
    const int j   = tid & 31;
    const float* w1 = grp ? b_w1 : w_w1;
    const float* b1 = grp ? b_b1 : w_b1;
    hraw[grp][j] = w1[j*3+0]*zs[0] + w1[j*3+1]*zs[1] + w1[j*3+2]*zs[2] + b1[j];
  }
  __syncthreads();

  if (tid < 2 * HID) {
    const int grp = tid >> 5;
    const int j   = tid & 31;
    float mu = 0.f;
    #pragma unroll
    for (int k = 0; k < HID; ++k) mu += hraw[grp][k];
    mu *= (1.0f / HID);
    float var = 0.f;
    #pragma unroll
    for (int k = 0; k < HID; ++k) { float d = hraw[grp][k] - mu; var += d * d; }
    var *= (1.0f / HID);
    const float r  = rsqrtf(var + 1e-5f);
    const float* g  = grp ? b_g    : w_g;
    const float* be = grp ? b_beta : w_beta;
    const float v = (hraw[grp][j] - mu) * r * g[j] + be[j];
    hn[grp][j] = fmaxf(v, 0.f);
  }
  __syncthreads();

  for (int m = tid; m < CH * CH; m += 256) {
    const float* row = w_w2 + m * HID;
    float acc = w_b2[m];
    #pragma unroll
    for (int i = 0; i < HID; ++i) acc += hn[0][i] * row[i];
    wbf[(size_t)b * CH * CH + m] = f2bf_bits(acc);
  }

  if (tid < CH) {
    const float* row = b_w2 + tid * HID;
    float acc = b_b2[tid];
    #pragma unroll
    for (int i = 0; i < HID; ++i) acc += hn[1][i] * row[i];
    bias[b * CH + tid] = acc;
  }
}

// ---------------------------------------------------------------------------
// Kernel 2: out[b] = W[b] (64x64) @ x[b] (64x4096) + bias via bf16 MFMA.
// Round-16 change: PAGE-SIZED ROW READS. Every 66-72us variant read x in
// 256 B-per-row visits at 16 KB stride (64 interleaved streams/block) ->
// DRAM page opens amortize only 256 B (copy kernels amortize 1-2 KB ->
// 6.3 TB/s). Here a block covers a 256-t tile; each global_load_lds reads
// ONE FULL ROW x 1024 B contiguous (64 lanes x 16 B = exactly the copy-
// kernel shape). 64 insts/block = 2 k-halves x 32. Accumulators persist
// across halves (f32x4 acc[4][4], literal indices only).
// LDS [64 k][260 pitch] + per-(k>>3) 8-float offset: compute ds_reads <=
// 2-way bank aliasing (free); staging dest = wave-uniform row base + HW
// lane*16 (linear, gload_lds-legal). Schedule per wave: stage H0(8)+H1(8);
// vmcnt(8)+bar -> MFMA ks=0; vmcnt(0)+bar -> MFMA ks=1 + stores.
// LDS 66944 B -> 2 blocks/CU; grid 16x128 = 2048 blocks.
// ---------------------------------------------------------------------------
#define STAGEH(H)                                                             \
  {                                                                           \
    _Pragma("unroll")                                                         \
    for (int q = 0; q < 8; ++q) {                                             \
      const int kp = wid * 8 + q;           /* row within half */             \
      const float* ga = xb + (size_t)(32 * (H) + kp) * T_LEN + lane * 4;      \
      __builtin_amdgcn_global_load_lds((gfloat1*)ga,                          \
          (sfloat3*)(lds + (H) * HALF_F + kp * PITCH + wid * 8), 16, 0, 0);   \
    }                                                                         \
  }

#define COMPKS(KS)                                                            \
  {                                                                           \
    _Pragma("unroll")                                                         \
    for (int nt = 0; nt < 4; ++nt) {                                          \
      union { short8 s; unsigned short u[8]; } bfv;                           \
      _Pragma("unroll")                                                       \
      for (int j = 0; j < 8; ++j) {                                           \
        const float f = lds[(KS) * HALF_F + (g * 8 + j) * PITCH + g * 8       \
                            + wid * 64 + nt * 16 + r];                        \
        bfv.u[j] = f2bf_bits(f);                                              \
      }                                                                       \
      acc[nt][0] = __builtin_amdgcn_mfma_f32_16x16x32_bf16(afrag[0][KS], bfv.s, acc[nt][0], 0, 0, 0); \
      acc[nt][1] = __builtin_amdgcn_mfma_f32_16x16x32_bf16(afrag[1][KS], bfv.s, acc[nt][1], 0, 0, 0); \
      acc[nt][2] = __builtin_amdgcn_mfma_f32_16x16x32_bf16(afrag[2][KS], bfv.s, acc[nt][2], 0, 0, 0); \
      acc[nt][3] = __builtin_amdgcn_mfma_f32_16x16x32_bf16(afrag[3][KS], bfv.s, acc[nt][3], 0, 0, 0); \
    }                                                                         \
  }

#define WAITB(N)                                                              \
  {                                                                           \
    asm volatile("s_waitcnt vmcnt(" #N ")" ::: "memory");                     \
    __builtin_amdgcn_s_barrier();                                             \
    asm volatile("" ::: "memory");                                            \
  }

__global__ __launch_bounds__(256, 2) void conv1x1_mfma(
    const float* __restrict__ x,
    const unsigned short* __restrict__ wbf,
    const float* __restrict__ bias,
    float* __restrict__ out)
{
  __shared__ __align__(16) float lds[2 * HALF_F];   // 66944 B -> 2 blocks/CU

  const int b    = blockIdx.y;
  const int tbi  = blockIdx.x;      // 256-t tile (0..15)
  const int tid  = threadIdx.x;
  const int lane = tid & 63;
  const int wid  = tid >> 6;        // 0..3 (uniform per wave)
  const int g    = lane >> 4;       // 16-lane group
  const int r    = lane & 15;

  // A-frags: wbf[b][ot*16 + r][ks*32 + g*8 + 0..7]  (8 x 16B loads)
  const unsigned short* wb = wbf + (size_t)b * CH * CH;
  short8 afrag[4][2];
  #pragma unroll
  for (int ot = 0; ot < 4; ++ot)
    #pragma unroll
    for (int ks = 0; ks < 2; ++ks)
      afrag[ot][ks] = *(const short8*)(wb + (ot * 16 + r) * CH + ks * 32 + g * 8);

  // bias for lane's output rows o = ot*16 + g*4 + q  (4 x 16B loads)
  float bv[4][4];
  #pragma unroll
  for (int ot = 0; ot < 4; ++ot) {
    const float4 t = *(const float4*)(bias + b * CH + ot * 16 + g * 4);
    bv[ot][0] = t.x; bv[ot][1] = t.y; bv[ot][2] = t.z; bv[ot][3] = t.w;
  }

  const float* xb = x   + (size_t)b * CH * T_LEN + tbi * 256;
  float*       ob = out + (size_t)b * CH * T_LEN + tbi * 256;

  // accumulators [nt][ot], bias-initialized; persist across both k-halves
  f32x4 acc[4][4];
  #pragma unroll
  for (int nt = 0; nt < 4; ++nt)
    #pragma unroll
    for (int ot = 0; ot < 4; ++ot) {
      f32x4 a = {bv[ot][0], bv[ot][1], bv[ot][2], bv[ot][3]};
      acc[nt][ot] = a;
    }

  STAGEH(0)
  STAGEH(1)

  WAITB(8)          // all waves' H0 resident (H1 may remain in flight)
  COMPKS(0)

  WAITB(0)          // H1 resident
  COMPKS(1)

  // stores: out[o = ot*16 + g*4 + qq][tbi*256 + wid*64 + nt*16 + r]
  #pragma unroll
  for (int nt = 0; nt < 4; ++nt) {
    float* os = ob + wid * 64 + nt * 16 + r;
    #pragma unroll
    for (int ot = 0; ot < 4; ++ot)
      #pragma unroll
      for (int qq = 0; qq < 4; ++qq)
        os[(size_t)(ot * 16 + g * 4 + qq) * T_LEN] = acc[nt][ot][qq];
  }
}

extern "C" void kernel_launch(void* const* d_in, const int* in_sizes, int n_in,
                              void* d_out, int out_size, void* d_ws, size_t ws_size,
                              hipStream_t stream) {
  const float* x      = (const float*)d_in[0];
  const float* z      = (const float*)d_in[1];
  const float* w_w1   = (const float*)d_in[2];
  const float* w_b1   = (const float*)d_in[3];
  const float* w_g    = (const float*)d_in[4];
  const float* w_beta = (const float*)d_in[5];
  const float* w_w2   = (const float*)d_in[6];
  const float* w_b2   = (const float*)d_in[7];
  const float* b_w1   = (const float*)d_in[8];
  const float* b_b1   = (const float*)d_in[9];
  const float* b_g    = (const float*)d_in[10];
  const float* b_beta = (const float*)d_in[11];
  const float* b_w2   = (const float*)d_in[12];
  const float* b_b2   = (const float*)d_in[13];

  float* out = (float*)d_out;
  unsigned short* wbf = (unsigned short*)d_ws;                 // 128*4096 bf16 = 1 MB
  float* bias = (float*)((char*)d_ws + (size_t)B_SZ * CH * CH * sizeof(unsigned short));

  hyper_mlp_kernel<<<B_SZ, 256, 0, stream>>>(
      z, w_w1, w_b1, w_g, w_beta, w_w2, w_b2,
      b_w1, b_b1, b_g, b_beta, b_w2, b_b2, wbf, bias);

  dim3 grid(T_LEN / 256, B_SZ);
  conv1x1_mfma<<<grid, 256, 0, stream>>>(x, wbf, bias, out);
}

// Round 17
// 65.142 us; speedup vs baseline: 1.2598x; 1.0148x over previous
//
#include <hip/hip_runtime.h>
#include <hip/hip_bf16.h>

#define B_SZ  128
#define CH    64
#define T_LEN 4096
#define HID   32
#define INS   3

#define PITCH  260      // floats per k-row in LDS (256 t + 4 pad)
#define HALF_F 8384     // floats per k-half (32 rows * 260 + 24 offset, 16B-aligned)

typedef __attribute__((ext_vector_type(8))) short short8;   // 8 bf16 (4 VGPRs)
typedef __attribute__((ext_vector_type(4))) float f32x4;
typedef __attribute__((address_space(1))) const float gfloat1;
typedef __attribute__((address_space(3))) float sfloat3;

__device__ inline unsigned short f2bf_bits(float f) {
  __hip_bfloat16 h = __float2bfloat16(f);
  union { __hip_bfloat16 h; unsigned short u; } cv;
  cv.h = h;
  return cv.u;
}

// ---------------------------------------------------------------------------
// Kernel 1: hypernetwork MLPs. One block per batch sample.
// Emits weight as bf16 in natural [b][o][i] order + fp32 bias.
// ---------------------------------------------------------------------------
__global__ __launch_bounds__(256) void hyper_mlp_kernel(
    const float* __restrict__ z,
    const float* __restrict__ w_w1, const float* __restrict__ w_b1,
    const float* __restrict__ w_g,  const float* __restrict__ w_beta,
    const float* __restrict__ w_w2, const float* __restrict__ w_b2,
    const float* __restrict__ b_w1, const float* __restrict__ b_b1,
    const float* __restrict__ b_g,  const float* __restrict__ b_beta,
    const float* __restrict__ b_w2, const float* __restrict__ b_b2,
    unsigned short* __restrict__ wbf,  // [B][CH_out][CH_in] bf16 bits
    float* __restrict__ bias)          // [B][CH]
{
  const int b   = blockIdx.x;
  const int tid = threadIdx.x;

  __shared__ float zs[INS];
  __shared__ float hraw[2][HID];
  __shared__ float hn[2][HID];

  if (tid < INS) zs[tid] = z[b * INS + tid];
  __syncthreads();

  if (tid < 2 * HID) {
    const int grp = tid >> 5;          // 0 = weight-MLP, 1 = bias-MLP
    const int j   = tid & 31;
    const float* w1 = grp ? b_w1 : w_w1;
    const float* b1 = grp ? b_b1 : w_b1;
    hraw[grp][j] = w1[j*3+0]*zs[0] + w1[j*3+1]*zs[1] + w1[j*3+2]*zs[2] + b1[j];
  }
  __syncthreads();

  if (tid < 2 * HID) {
    const int grp = tid >> 5;
    const int j   = tid & 31;
    float mu = 0.f;
    #pragma unroll
    for (int k = 0; k < HID; ++k) mu += hraw[grp][k];
    mu *= (1.0f / HID);
    float var = 0.f;
    #pragma unroll
    for (int k = 0; k < HID; ++k) { float d = hraw[grp][k] - mu; var += d * d; }
    var *= (1.0f / HID);
    const float r  = rsqrtf(var + 1e-5f);
    const float* g  = grp ? b_g    : w_g;
    const float* be = grp ? b_beta : w_beta;
    const float v = (hraw[grp][j] - mu) * r * g[j] + be[j];
    hn[grp][j] = fmaxf(v, 0.f);
  }
  __syncthreads();

  for (int m = tid; m < CH * CH; m += 256) {
    const float* row = w_w2 + m * HID;
    float acc = w_b2[m];
    #pragma unroll
    for (int i = 0; i < HID; ++i) acc += hn[0][i] * row[i];
    wbf[(size_t)b * CH * CH + m] = f2bf_bits(acc);
  }

  if (tid < CH) {
    const float* row = b_w2 + tid * HID;
    float acc = b_b2[tid];
    #pragma unroll
    for (int i = 0; i < HID; ++i) acc += hn[1][i] * row[i];
    bias[b * CH + tid] = acc;
  }
}

// ---------------------------------------------------------------------------
// Kernel 2: out[b] = W[b] (64x64) @ x[b] (64x4096) + bias via bf16 MFMA.
// Round-17 change vs r16 (byte-identical staging/compute): STORE SHAPE.
// r16 stores wrote 4 o-rows x 64 B per instruction (global_store_dword,
// 16 KB row stride) -> each DRAM page visit amortizes only 64 B. fillBuffer
// (6.9 TB/s measured on-chip) writes 1 KB contiguous per inst. Here, after
// COMPKS(1) the staging LDS is dead, so we overlay a [64 o][260] transpose
// buffer (zero extra LDS): acc -> xp (4 B LDS writes, 2-way banks = free),
// lgkmcnt(0)+barrier, then each wave sweeps its 16 o-rows with ds_read_b128
// + global_store_dwordx4 = 1 KB contiguous per store inst. tbi-adjacent
// blocks write adjacent 1 KB segments of the same rows -> near-sequential
// per-row write streams at the controllers.
// ---------------------------------------------------------------------------
#define STAGEH(H)                                                             \
  {                                                                           \
    _Pragma("unroll")                                                         \
    for (int q = 0; q < 8; ++q) {                                             \
      const int kp = wid * 8 + q;           /* row within half */             \
      const float* ga = xb + (size_t)(32 * (H) + kp) * T_LEN + lane * 4;      \
      __builtin_amdgcn_global_load_lds((gfloat1*)ga,                          \
          (sfloat3*)(lds + (H) * HALF_F + kp * PITCH + wid * 8), 16, 0, 0);   \
    }                                                                         \
  }

#define COMPKS(KS)                                                            \
  {                                                                           \
    _Pragma("unroll")                                                         \
    for (int nt = 0; nt < 4; ++nt) {                                          \
      union { short8 s; unsigned short u[8]; } bfv;                           \
      _Pragma("unroll")                                                       \
      for (int j = 0; j < 8; ++j) {                                           \
        const float f = lds[(KS) * HALF_F + (g * 8 + j) * PITCH + g * 8       \
                            + wid * 64 + nt * 16 + r];                        \
        bfv.u[j] = f2bf_bits(f);                                              \
      }                                                                       \
      acc[nt][0] = __builtin_amdgcn_mfma_f32_16x16x32_bf16(afrag[0][KS], bfv.s, acc[nt][0], 0, 0, 0); \
      acc[nt][1] = __builtin_amdgcn_mfma_f32_16x16x32_bf16(afrag[1][KS], bfv.s, acc[nt][1], 0, 0, 0); \
      acc[nt][2] = __builtin_amdgcn_mfma_f32_16x16x32_bf16(afrag[2][KS], bfv.s, acc[nt][2], 0, 0, 0); \
      acc[nt][3] = __builtin_amdgcn_mfma_f32_16x16x32_bf16(afrag[3][KS], bfv.s, acc[nt][3], 0, 0, 0); \
    }                                                                         \
  }

#define WAITB(N)                                                              \
  {                                                                           \
    asm volatile("s_waitcnt vmcnt(" #N ")" ::: "memory");                     \
    __builtin_amdgcn_s_barrier();                                             \
    asm volatile("" ::: "memory");                                            \
  }

#define LGKMB                                                                 \
  {                                                                           \
    asm volatile("s_waitcnt lgkmcnt(0)" ::: "memory");                        \
    __builtin_amdgcn_s_barrier();                                             \
    asm volatile("" ::: "memory");                                            \
  }

__global__ __launch_bounds__(256, 2) void conv1x1_mfma(
    const float* __restrict__ x,
    const unsigned short* __restrict__ wbf,
    const float* __restrict__ bias,
    float* __restrict__ out)
{
  __shared__ __align__(16) float lds[2 * HALF_F];   // 67072 B -> 2 blocks/CU

  const int b    = blockIdx.y;
  const int tbi  = blockIdx.x;      // 256-t tile (0..15)
  const int tid  = threadIdx.x;
  const int lane = tid & 63;
  const int wid  = tid >> 6;        // 0..3 (uniform per wave)
  const int g    = lane >> 4;       // 16-lane group
  const int r    = lane & 15;

  // A-frags: wbf[b][ot*16 + r][ks*32 + g*8 + 0..7]  (8 x 16B loads)
  const unsigned short* wb = wbf + (size_t)b * CH * CH;
  short8 afrag[4][2];
  #pragma unroll
  for (int ot = 0; ot < 4; ++ot)
    #pragma unroll
    for (int ks = 0; ks < 2; ++ks)
      afrag[ot][ks] = *(const short8*)(wb + (ot * 16 + r) * CH + ks * 32 + g * 8);

  // bias for lane's output rows o = ot*16 + g*4 + q  (4 x 16B loads)
  float bv[4][4];
  #pragma unroll
  for (int ot = 0; ot < 4; ++ot) {
    const float4 t = *(const float4*)(bias + b * CH + ot * 16 + g * 4);
    bv[ot][0] = t.x; bv[ot][1] = t.y; bv[ot][2] = t.z; bv[ot][3] = t.w;
  }

  const float* xb = x   + (size_t)b * CH * T_LEN + tbi * 256;
  float*       ob = out + (size_t)b * CH * T_LEN + tbi * 256;

  // accumulators [nt][ot], bias-initialized; persist across both k-halves
  f32x4 acc[4][4];
  #pragma unroll
  for (int nt = 0; nt < 4; ++nt)
    #pragma unroll
    for (int ot = 0; ot < 4; ++ot) {
      f32x4 a = {bv[ot][0], bv[ot][1], bv[ot][2], bv[ot][3]};
      acc[nt][ot] = a;
    }

  STAGEH(0)
  STAGEH(1)

  WAITB(8)          // all waves' H0 resident (H1 may remain in flight)
  COMPKS(0)

  WAITB(0)          // H1 resident
  COMPKS(1)

  // ---- transpose through (dead) staging LDS, then 1 KB-contiguous stores --
  LGKMB             // all ds_reads retired in every wave -> safe to overwrite

  // xp[o][t'] at lds[o*PITCH + t']; thread writes its 16 acc quads.
  #pragma unroll
  for (int nt = 0; nt < 4; ++nt)
    #pragma unroll
    for (int ot = 0; ot < 4; ++ot)
      #pragma unroll
      for (int qq = 0; qq < 4; ++qq)
        lds[(ot * 16 + g * 4 + qq) * PITCH + wid * 64 + nt * 16 + r] =
            acc[nt][ot][qq];

  LGKMB             // xp visible to all waves

  // wave w stores rows o = w*16 .. w*16+15; per row: one ds_read_b128 +
  // one global_store_dwordx4 covering 1024 B contiguous of out[b][o][.].
  #pragma unroll
  for (int j = 0; j < 16; ++j) {
    const int o = wid * 16 + j;
    const float4 v = *(const float4*)(&lds[o * PITCH + lane * 4]);
    *(float4*)(&ob[(size_t)o * T_LEN + lane * 4]) = v;
  }
}

extern "C" void kernel_launch(void* const* d_in, const int* in_sizes, int n_in,
                              void* d_out, int out_size, void* d_ws, size_t ws_size,
                              hipStream_t stream) {
  const float* x      = (const float*)d_in[0];
  const float* z      = (const float*)d_in[1];
  const float* w_w1   = (const float*)d_in[2];
  const float* w_b1   = (const float*)d_in[3];
  const float* w_g    = (const float*)d_in[4];
  const float* w_beta = (const float*)d_in[5];
  const float* w_w2   = (const float*)d_in[6];
  const float* w_b2   = (const float*)d_in[7];
  const float* b_w1   = (const float*)d_in[8];
  const float* b_b1   = (const float*)d_in[9];
  const float* b_g    = (const float*)d_in[10];
  const float* b_beta = (const float*)d_in[11];
  const float* b_w2   = (const float*)d_in[12];
  const float* b_b2   = (const float*)d_in[13];

  float* out = (float*)d_out;
  unsigned short* wbf = (unsigned short*)d_ws;                 // 128*4096 bf16 = 1 MB
  float* bias = (float*)((char*)d_ws + (size_t)B_SZ * CH * CH * sizeof(unsigned short));

  hyper_mlp_kernel<<<B_SZ, 256, 0, stream>>>(
      z, w_w1, w_b1, w_g, w_beta, w_w2, w_b2,
      b_w1, b_b1, b_g, b_beta, b_w2, b_b2, wbf, bias);

  dim3 grid(T_LEN / 256, B_SZ);
  conv1x1_mfma<<<grid, 256, 0, stream>>>(x, wbf, bias, out);
}

// Round 18
// 60.208 us; speedup vs baseline: 1.3630x; 1.0820x over previous
//
#include <hip/hip_runtime.h>
#include <hip/hip_bf16.h>

#define B_SZ  128
#define CH    64
#define T_LEN 4096
#define HID   32
#define INS   3

#define PITCH  260      // floats per k-row in LDS (256 t + 4 pad)
#define HALF_F 8384     // floats per k-half (32 rows * 260 + 24 offset, 16B-aligned)

typedef __attribute__((ext_vector_type(8))) short short8;   // 8 bf16 (4 VGPRs)
typedef __attribute__((ext_vector_type(4))) float f32x4;
typedef __attribute__((address_space(1))) const float gfloat1;
typedef __attribute__((address_space(3))) float sfloat3;

__device__ inline unsigned short f2bf_bits(float f) {
  __hip_bfloat16 h = __float2bfloat16(f);
  union { __hip_bfloat16 h; unsigned short u; } cv;
  cv.h = h;
  return cv.u;
}

// ---------------------------------------------------------------------------
// Kernel 1 (round-18 rework): 512 blocks = 4 per sample; each block computes
// a 1024-entry quarter of the weight head with float4-vectorized w_w2 reads
// (64 VMEM insts/thread vs 512 scalar before) and redundantly-computed hn
// (trivial). Bias head in quarter 0. Was ~4-5us at 128 blocks w/ scalar
// loads; target ~1-1.5us.
// ---------------------------------------------------------------------------
__global__ __launch_bounds__(256) void hyper_mlp_kernel(
    const float* __restrict__ z,
    const float* __restrict__ w_w1, const float* __restrict__ w_b1,
    const float* __restrict__ w_g,  const float* __restrict__ w_beta,
    const float* __restrict__ w_w2, const float* __restrict__ w_b2,
    const float* __restrict__ b_w1, const float* __restrict__ b_b1,
    const float* __restrict__ b_g,  const float* __restrict__ b_beta,
    const float* __restrict__ b_w2, const float* __restrict__ b_b2,
    unsigned short* __restrict__ wbf,  // [B][CH_out][CH_in] bf16 bits
    float* __restrict__ bias)          // [B][CH]
{
  const int blk = blockIdx.x;
  const int b   = blk >> 2;
  const int qt  = blk & 3;          // 1024-entry quarter of the weight head
  const int tid = threadIdx.x;

  __shared__ float zs[INS];
  __shared__ float hraw[2][HID];
  __shared__ float hn[2][HID];

  if (tid < INS) zs[tid] = z[b * INS + tid];
  __syncthreads();

  if (tid < 2 * HID) {
    const int grp = tid >> 5;          // 0 = weight-MLP, 1 = bias-MLP
    const int j   = tid & 31;
    const float* w1 = grp ? b_w1 : w_w1;
    const float* b1 = grp ? b_b1 : w_b1;
    hraw[grp][j] = w1[j*3+0]*zs[0] + w1[j*3+1]*zs[1] + w1[j*3+2]*zs[2] + b1[j];
  }
  __syncthreads();

  if (tid < 2 * HID) {
    const int grp = tid >> 5;
    const int j   = tid & 31;
    float mu = 0.f;
    #pragma unroll
    for (int k = 0; k < HID; ++k) mu += hraw[grp][k];
    mu *= (1.0f / HID);
    float var = 0.f;
    #pragma unroll
    for (int k = 0; k < HID; ++k) { float d = hraw[grp][k] - mu; var += d * d; }
    var *= (1.0f / HID);
    const float r  = rsqrtf(var + 1e-5f);
    const float* g  = grp ? b_g    : w_g;
    const float* be = grp ? b_beta : w_beta;
    const float v = (hraw[grp][j] - mu) * r * g[j] + be[j];
    hn[grp][j] = fmaxf(v, 0.f);
  }
  __syncthreads();

  // hoist hn[0][*] into registers (8 float4 worth)
  float h0[HID];
  #pragma unroll
  for (int j = 0; j < HID; ++j) h0[j] = hn[0][j];

  // weight head quarter: 1024 entries, 4 per thread, float4 row reads
  #pragma unroll
  for (int e = 0; e < 4; ++e) {
    const int m = qt * 1024 + e * 256 + tid;
    const float4* row = (const float4*)(w_w2 + (size_t)m * HID);
    float acc = w_b2[m];
    #pragma unroll
    for (int qq = 0; qq < 8; ++qq) {
      const float4 v = row[qq];
      acc += h0[qq*4+0] * v.x + h0[qq*4+1] * v.y
           + h0[qq*4+2] * v.z + h0[qq*4+3] * v.w;
    }
    wbf[(size_t)b * CH * CH + m] = f2bf_bits(acc);
  }

  // bias head: quarter 0 only
  if (qt == 0 && tid < CH) {
    const float4* row = (const float4*)(b_w2 + (size_t)tid * HID);
    float acc = b_b2[tid];
    #pragma unroll
    for (int qq = 0; qq < 8; ++qq) {
      const float4 v = row[qq];
      acc += hn[1][qq*4+0] * v.x + hn[1][qq*4+1] * v.y
           + hn[1][qq*4+2] * v.z + hn[1][qq*4+3] * v.w;
    }
    bias[b * CH + tid] = acc;
  }
}

// ---------------------------------------------------------------------------
// Kernel 2: byte-identical round 17 (best: 65.1 us).
// out[b] = W[b] (64x64) @ x[b] (64x4096) + bias via bf16 MFMA.
// 1 KB-contiguous row reads (global_load_lds, r16) + 1 KB-contiguous row
// stores via dead-staging-LDS transpose (r17).
// ---------------------------------------------------------------------------
#define STAGEH(H)                                                             \
  {                                                                           \
    _Pragma("unroll")                                                         \
    for (int q = 0; q < 8; ++q) {                                             \
      const int kp = wid * 8 + q;           /* row within half */             \
      const float* ga = xb + (size_t)(32 * (H) + kp) * T_LEN + lane * 4;      \
      __builtin_amdgcn_global_load_lds((gfloat1*)ga,                          \
          (sfloat3*)(lds + (H) * HALF_F + kp * PITCH + wid * 8), 16, 0, 0);   \
    }                                                                         \
  }

#define COMPKS(KS)                                                            \
  {                                                                           \
    _Pragma("unroll")                                                         \
    for (int nt = 0; nt < 4; ++nt) {                                          \
      union { short8 s; unsigned short u[8]; } bfv;                           \
      _Pragma("unroll")                                                       \
      for (int j = 0; j < 8; ++j) {                                           \
        const float f = lds[(KS) * HALF_F + (g * 8 + j) * PITCH + g * 8       \
                            + wid * 64 + nt * 16 + r];                        \
        bfv.u[j] = f2bf_bits(f);                                              \
      }                                                                       \
      acc[nt][0] = __builtin_amdgcn_mfma_f32_16x16x32_bf16(afrag[0][KS], bfv.s, acc[nt][0], 0, 0, 0); \
      acc[nt][1] = __builtin_amdgcn_mfma_f32_16x16x32_bf16(afrag[1][KS], bfv.s, acc[nt][1], 0, 0, 0); \
      acc[nt][2] = __builtin_amdgcn_mfma_f32_16x16x32_bf16(afrag[2][KS], bfv.s, acc[nt][2], 0, 0, 0); \
      acc[nt][3] = __builtin_amdgcn_mfma_f32_16x16x32_bf16(afrag[3][KS], bfv.s, acc[nt][3], 0, 0, 0); \
    }                                                                         \
  }

#define WAITB(N)                                                              \
  {                                                                           \
    asm volatile("s_waitcnt vmcnt(" #N ")" ::: "memory");                     \
    __builtin_amdgcn_s_barrier();                                             \
    asm volatile("" ::: "memory");                                            \
  }

#define LGKMB                                                                 \
  {                                                                           \
    asm volatile("s_waitcnt lgkmcnt(0)" ::: "memory");                        \
    __builtin_amdgcn_s_barrier();                                             \
    asm volatile("" ::: "memory");                                            \
  }

__global__ __launch_bounds__(256, 2) void conv1x1_mfma(
    const float* __restrict__ x,
    const unsigned short* __restrict__ wbf,
    const float* __restrict__ bias,
    float* __restrict__ out)
{
  __shared__ __align__(16) float lds[2 * HALF_F];   // 67072 B -> 2 blocks/CU

  const int b    = blockIdx.y;
  const int tbi  = blockIdx.x;      // 256-t tile (0..15)
  const int tid  = threadIdx.x;
  const int lane = tid & 63;
  const int wid  = tid >> 6;        // 0..3 (uniform per wave)
  const int g    = lane >> 4;       // 16-lane group
  const int r    = lane & 15;

  // A-frags: wbf[b][ot*16 + r][ks*32 + g*8 + 0..7]  (8 x 16B loads)
  const unsigned short* wb = wbf + (size_t)b * CH * CH;
  short8 afrag[4][2];
  #pragma unroll
  for (int ot = 0; ot < 4; ++ot)
    #pragma unroll
    for (int ks = 0; ks < 2; ++ks)
      afrag[ot][ks] = *(const short8*)(wb + (ot * 16 + r) * CH + ks * 32 + g * 8);

  // bias for lane's output rows o = ot*16 + g*4 + q  (4 x 16B loads)
  float bv[4][4];
  #pragma unroll
  for (int ot = 0; ot < 4; ++ot) {
    const float4 t = *(const float4*)(bias + b * CH + ot * 16 + g * 4);
    bv[ot][0] = t.x; bv[ot][1] = t.y; bv[ot][2] = t.z; bv[ot][3] = t.w;
  }

  const float* xb = x   + (size_t)b * CH * T_LEN + tbi * 256;
  float*       ob = out + (size_t)b * CH * T_LEN + tbi * 256;

  // accumulators [nt][ot], bias-initialized; persist across both k-halves
  f32x4 acc[4][4];
  #pragma unroll
  for (int nt = 0; nt < 4; ++nt)
    #pragma unroll
    for (int ot = 0; ot < 4; ++ot) {
      f32x4 a = {bv[ot][0], bv[ot][1], bv[ot][2], bv[ot][3]};
      acc[nt][ot] = a;
    }

  STAGEH(0)
  STAGEH(1)

  WAITB(8)          // all waves' H0 resident (H1 may remain in flight)
  COMPKS(0)

  WAITB(0)          // H1 resident
  COMPKS(1)

  // ---- transpose through (dead) staging LDS, then 1 KB-contiguous stores --
  LGKMB             // all ds_reads retired in every wave -> safe to overwrite

  // xp[o][t'] at lds[o*PITCH + t']; thread writes its 16 acc quads.
  #pragma unroll
  for (int nt = 0; nt < 4; ++nt)
    #pragma unroll
    for (int ot = 0; ot < 4; ++ot)
      #pragma unroll
      for (int qq = 0; qq < 4; ++qq)
        lds[(ot * 16 + g * 4 + qq) * PITCH + wid * 64 + nt * 16 + r] =
            acc[nt][ot][qq];

  LGKMB             // xp visible to all waves

  // wave w stores rows o = w*16 .. w*16+15; per row: one ds_read_b128 +
  // one global_store_dwordx4 covering 1024 B contiguous of out[b][o][.].
  #pragma unroll
  for (int j = 0; j < 16; ++j) {
    const int o = wid * 16 + j;
    const float4 v = *(const float4*)(&lds[o * PITCH + lane * 4]);
    *(float4*)(&ob[(size_t)o * T_LEN + lane * 4]) = v;
  }
}

extern "C" void kernel_launch(void* const* d_in, const int* in_sizes, int n_in,
                              void* d_out, int out_size, void* d_ws, size_t ws_size,
                              hipStream_t stream) {
  const float* x      = (const float*)d_in[0];
  const float* z      = (const float*)d_in[1];
  const float* w_w1   = (const float*)d_in[2];
  const float* w_b1   = (const float*)d_in[3];
  const float* w_g    = (const float*)d_in[4];
  const float* w_beta = (const float*)d_in[5];
  const float* w_w2   = (const float*)d_in[6];
  const float* w_b2   = (const float*)d_in[7];
  const float* b_w1   = (const float*)d_in[8];
  const float* b_b1   = (const float*)d_in[9];
  const float* b_g    = (const float*)d_in[10];
  const float* b_beta = (const float*)d_in[11];
  const float* b_w2   = (const float*)d_in[12];
  const float* b_b2   = (const float*)d_in[13];

  float* out = (float*)d_out;
  unsigned short* wbf = (unsigned short*)d_ws;                 // 128*4096 bf16 = 1 MB
  float* bias = (float*)((char*)d_ws + (size_t)B_SZ * CH * CH * sizeof(unsigned short));

  hyper_mlp_kernel<<<B_SZ * 4, 256, 0, stream>>>(
      z, w_w1, w_b1, w_g, w_beta, w_w2, w_b2,
      b_w1, b_b1, b_g, b_beta, b_w2, b_b2, wbf, bias);

  dim3 grid(T_LEN / 256, B_SZ);
  conv1x1_mfma<<<grid, 256, 0, stream>>>(x, wbf, bias, out);
}

// Round 20
// 59.400 us; speedup vs baseline: 1.3816x; 1.0136x over previous
//
#include <hip/hip_runtime.h>
#include <hip/hip_bf16.h>

#define B_SZ  128
#define CH    64
#define T_LEN 4096
#define HID   32
#define INS   3

#define PITCH  260      // floats per k-row in LDS (256 t + 4 pad)
#define HALF_F 8384     // floats per k-half (32 rows * 260 + 24 offset, 16B-aligned)

typedef __attribute__((ext_vector_type(8))) short short8;   // 8 bf16 (4 VGPRs)
typedef __attribute__((ext_vector_type(4))) float f32x4;
typedef __attribute__((address_space(1))) const float gfloat1;
typedef __attribute__((address_space(3))) float sfloat3;

__device__ inline unsigned short f2bf_bits(float f) {
  __hip_bfloat16 h = __float2bfloat16(f);
  union { __hip_bfloat16 h; unsigned short u; } cv;
  cv.h = h;
  return cv.u;
}

// ---------------------------------------------------------------------------
// Kernel 1 (r18): 512 blocks = 4 per sample; float4-vectorized w_w2 reads.
// ---------------------------------------------------------------------------
__global__ __launch_bounds__(256) void hyper_mlp_kernel(
    const float* __restrict__ z,
    const float* __restrict__ w_w1, const float* __restrict__ w_b1,
    const float* __restrict__ w_g,  const float* __restrict__ w_beta,
    const float* __restrict__ w_w2, const float* __restrict__ w_b2,
    const float* __restrict__ b_w1, const float* __restrict__ b_b1,
    const float* __restrict__ b_g,  const float* __restrict__ b_beta,
    const float* __restrict__ b_w2, const float* __restrict__ b_b2,
    unsigned short* __restrict__ wbf,  // [B][CH_out][CH_in] bf16 bits
    float* __restrict__ bias)          // [B][CH]
{
  const int blk = blockIdx.x;
  const int b   = blk >> 2;
  const int qt  = blk & 3;          // 1024-entry quarter of the weight head
  const int tid = threadIdx.x;

  __shared__ float zs[INS];
  __shared__ float hraw[2][HID];
  __shared__ float hn[2][HID];

  if (tid < INS) zs[tid] = z[b * INS + tid];
  __syncthreads();

  if (tid < 2 * HID) {
    const int grp = tid >> 5;          // 0 = weight-MLP, 1 = bias-MLP
    const int j   = tid & 31;
    const float* w1 = grp ? b_w1 : w_w1;
    const float* b1 = grp ? b_b1 : w_b1;
    hraw[grp][j] = w1[j*3+0]*zs[0] + w1[j*3+1]*zs[1] + w1[j*3+2]*zs[2] + b1[j];
  }
  __syncthreads();

  if (tid < 2 * HID) {
    const int grp = tid >> 5;
    const int j   = tid & 31;
    float mu = 0.f;
    #pragma unroll
    for (int k = 0; k < HID; ++k) mu += hraw[grp][k];
    mu *= (1.0f / HID);
    float var = 0.f;
    #pragma unroll
    for (int k = 0; k < HID; ++k) { float d = hraw[grp][k] - mu; var += d * d; }
    var *= (1.0f / HID);
    const float r  = rsqrtf(var + 1e-5f);
    const float* g  = grp ? b_g    : w_g;
    const float* be = grp ? b_beta : w_beta;
    const float v = (hraw[grp][j] - mu) * r * g[j] + be[j];
    hn[grp][j] = fmaxf(v, 0.f);
  }
  __syncthreads();

  float h0[HID];
  #pragma unroll
  for (int j = 0; j < HID; ++j) h0[j] = hn[0][j];

  #pragma unroll
  for (int e = 0; e < 4; ++e) {
    const int m = qt * 1024 + e * 256 + tid;
    const float4* row = (const float4*)(w_w2 + (size_t)m * HID);
    float acc = w_b2[m];
    #pragma unroll
    for (int qq = 0; qq < 8; ++qq) {
      const float4 v = row[qq];
      acc += h0[qq*4+0] * v.x + h0[qq*4+1] * v.y
           + h0[qq*4+2] * v.z + h0[qq*4+3] * v.w;
    }
    wbf[(size_t)b * CH * CH + m] = f2bf_bits(acc);
  }

  if (qt == 0 && tid < CH) {
    const float4* row = (const float4*)(b_w2 + (size_t)tid * HID);
    float acc = b_b2[tid];
    #pragma unroll
    for (int qq = 0; qq < 8; ++qq) {
      const float4 v = row[qq];
      acc += hn[1][qq*4+0] * v.x + hn[1][qq*4+1] * v.y
           + hn[1][qq*4+2] * v.z + hn[1][qq*4+3] * v.w;
    }
    bias[b * CH + tid] = acc;
  }
}

// ---------------------------------------------------------------------------
// Kernel 2: r17/r18 structure; single change: the final 1 KB-contiguous
// store sweep is NON-TEMPORAL (ext-vector f32x4 — clang vector type, which
// __builtin_nontemporal_store accepts; HIP float4 struct is rejected).
// Theory: out never allocates in L3 -> x (134 MB) becomes ~fully
// L3-resident -> FETCH collapses; HBM carries only the streaming write.
// ---------------------------------------------------------------------------
#define STAGEH(H)                                                             \
  {                                                                           \
    _Pragma("unroll")                                                         \
    for (int q = 0; q < 8; ++q) {                                             \
      const int kp = wid * 8 + q;           /* row within half */             \
      const float* ga = xb + (size_t)(32 * (H) + kp) * T_LEN + lane * 4;      \
      __builtin_amdgcn_global_load_lds((gfloat1*)ga,                          \
          (sfloat3*)(lds + (H) * HALF_F + kp * PITCH + wid * 8), 16, 0, 0);   \
    }                                                                         \
  }

#define COMPKS(KS)                                                            \
  {                                                                           \
    _Pragma("unroll")                                                         \
    for (int nt = 0; nt < 4; ++nt) {                                          \
      union { short8 s; unsigned short u[8]; } bfv;                           \
      _Pragma("unroll")                                                       \
      for (int j = 0; j < 8; ++j) {                                           \
        const float f = lds[(KS) * HALF_F + (g * 8 + j) * PITCH + g * 8       \
                            + wid * 64 + nt * 16 + r];                        \
        bfv.u[j] = f2bf_bits(f);                                              \
      }                                                                       \
      acc[nt][0] = __builtin_amdgcn_mfma_f32_16x16x32_bf16(afrag[0][KS], bfv.s, acc[nt][0], 0, 0, 0); \
      acc[nt][1] = __builtin_amdgcn_mfma_f32_16x16x32_bf16(afrag[1][KS], bfv.s, acc[nt][1], 0, 0, 0); \
      acc[nt][2] = __builtin_amdgcn_mfma_f32_16x16x32_bf16(afrag[2][KS], bfv.s, acc[nt][2], 0, 0, 0); \
      acc[nt][3] = __builtin_amdgcn_mfma_f32_16x16x32_bf16(afrag[3][KS], bfv.s, acc[nt][3], 0, 0, 0); \
    }                                                                         \
  }

#define WAITB(N)                                                              \
  {                                                                           \
    asm volatile("s_waitcnt vmcnt(" #N ")" ::: "memory");                     \
    __builtin_amdgcn_s_barrier();                                             \
    asm volatile("" ::: "memory");                                            \
  }

#define LGKMB                                                                 \
  {                                                                           \
    asm volatile("s_waitcnt lgkmcnt(0)" ::: "memory");                        \
    __builtin_amdgcn_s_barrier();                                             \
    asm volatile("" ::: "memory");                                            \
  }

__global__ __launch_bounds__(256, 2) void conv1x1_mfma(
    const float* __restrict__ x,
    const unsigned short* __restrict__ wbf,
    const float* __restrict__ bias,
    float* __restrict__ out)
{
  __shared__ __align__(16) float lds[2 * HALF_F];   // 67072 B -> 2 blocks/CU

  const int b    = blockIdx.y;
  const int tbi  = blockIdx.x;      // 256-t tile (0..15)
  const int tid  = threadIdx.x;
  const int lane = tid & 63;
  const int wid  = tid >> 6;        // 0..3 (uniform per wave)
  const int g    = lane >> 4;       // 16-lane group
  const int r    = lane & 15;

  // A-frags: wbf[b][ot*16 + r][ks*32 + g*8 + 0..7]  (8 x 16B loads)
  const unsigned short* wb = wbf + (size_t)b * CH * CH;
  short8 afrag[4][2];
  #pragma unroll
  for (int ot = 0; ot < 4; ++ot)
    #pragma unroll
    for (int ks = 0; ks < 2; ++ks)
      afrag[ot][ks] = *(const short8*)(wb + (ot * 16 + r) * CH + ks * 32 + g * 8);

  // bias for lane's output rows o = ot*16 + g*4 + q  (4 x 16B loads)
  float bv[4][4];
  #pragma unroll
  for (int ot = 0; ot < 4; ++ot) {
    const float4 t = *(const float4*)(bias + b * CH + ot * 16 + g * 4);
    bv[ot][0] = t.x; bv[ot][1] = t.y; bv[ot][2] = t.z; bv[ot][3] = t.w;
  }

  const float* xb = x   + (size_t)b * CH * T_LEN + tbi * 256;
  float*       ob = out + (size_t)b * CH * T_LEN + tbi * 256;

  // accumulators [nt][ot], bias-initialized; persist across both k-halves
  f32x4 acc[4][4];
  #pragma unroll
  for (int nt = 0; nt < 4; ++nt)
    #pragma unroll
    for (int ot = 0; ot < 4; ++ot) {
      f32x4 a = {bv[ot][0], bv[ot][1], bv[ot][2], bv[ot][3]};
      acc[nt][ot] = a;
    }

  STAGEH(0)
  STAGEH(1)

  WAITB(8)          // all waves' H0 resident (H1 may remain in flight)
  COMPKS(0)

  WAITB(0)          // H1 resident
  COMPKS(1)

  // ---- transpose through (dead) staging LDS, then 1 KB-contiguous stores --
  LGKMB             // all ds_reads retired in every wave -> safe to overwrite

  #pragma unroll
  for (int nt = 0; nt < 4; ++nt)
    #pragma unroll
    for (int ot = 0; ot < 4; ++ot)
      #pragma unroll
      for (int qq = 0; qq < 4; ++qq)
        lds[(ot * 16 + g * 4 + qq) * PITCH + wid * 64 + nt * 16 + r] =
            acc[nt][ot][qq];

  LGKMB             // xp visible to all waves

  // wave w stores rows o = w*16 .. w*16+15; per row one 1 KB-contiguous
  // NON-TEMPORAL dwordx4 store sweep (no L3 allocation). ext-vector f32x4.
  #pragma unroll
  for (int j = 0; j < 16; ++j) {
    const int o = wid * 16 + j;
    const f32x4 v = *(const f32x4*)(&lds[o * PITCH + lane * 4]);
    __builtin_nontemporal_store(v, (f32x4*)(&ob[(size_t)o * T_LEN + lane * 4]));
  }
}

extern "C" void kernel_launch(void* const* d_in, const int* in_sizes, int n_in,
                              void* d_out, int out_size, void* d_ws, size_t ws_size,
                              hipStream_t stream) {
  const float* x      = (const float*)d_in[0];
  const float* z      = (const float*)d_in[1];
  const float* w_w1   = (const float*)d_in[2];
  const float* w_b1   = (const float*)d_in[3];
  const float* w_g    = (const float*)d_in[4];
  const float* w_beta = (const float*)d_in[5];
  const float* w_w2   = (const float*)d_in[6];
  const float* w_b2   = (const float*)d_in[7];
  const float* b_w1   = (const float*)d_in[8];
  const float* b_b1   = (const float*)d_in[9];
  const float* b_g    = (const float*)d_in[10];
  const float* b_beta = (const float*)d_in[11];
  const float* b_w2   = (const float*)d_in[12];
  const float* b_b2   = (const float*)d_in[13];

  float* out = (float*)d_out;
  unsigned short* wbf = (unsigned short*)d_ws;                 // 128*4096 bf16 = 1 MB
  float* bias = (float*)((char*)d_ws + (size_t)B_SZ * CH * CH * sizeof(unsigned short));

  hyper_mlp_kernel<<<B_SZ * 4, 256, 0, stream>>>(
      z, w_w1, w_b1, w_g, w_beta, w_w2, w_b2,
      b_w1, b_b1, b_g, b_beta, b_w2, b_b2, wbf, bias);

  dim3 grid(T_LEN / 256, B_SZ);
  conv1x1_mfma<<<grid, 256, 0, stream>>>(x, wbf, bias, out);
}

// Round 21
// 58.393 us; speedup vs baseline: 1.4054x; 1.0172x over previous
//
#include <hip/hip_runtime.h>
#include <hip/hip_bf16.h>

#define B_SZ  128
#define CH    64
#define T_LEN 4096
#define HID   32
#define INS   3

#define PPITCH 268      // floats per k-ROW-PAIR in LDS (2x128 t + 12 pad; 1072 B, 16B-aligned)

typedef __attribute__((ext_vector_type(8))) short short8;   // 8 bf16 (4 VGPRs)
typedef __attribute__((ext_vector_type(4))) float f32x4;
typedef __attribute__((address_space(1))) const float gfloat1;
typedef __attribute__((address_space(3))) float sfloat3;

__device__ inline unsigned short f2bf_bits(float f) {
  __hip_bfloat16 h = __float2bfloat16(f);
  union { __hip_bfloat16 h; unsigned short u; } cv;
  cv.h = h;
  return cv.u;
}

// ---------------------------------------------------------------------------
// Kernel 1 (r18): 512 blocks = 4 per sample; float4-vectorized w_w2 reads.
// ---------------------------------------------------------------------------
__global__ __launch_bounds__(256) void hyper_mlp_kernel(
    const float* __restrict__ z,
    const float* __restrict__ w_w1, const float* __restrict__ w_b1,
    const float* __restrict__ w_g,  const float* __restrict__ w_beta,
    const float* __restrict__ w_w2, const float* __restrict__ w_b2,
    const float* __restrict__ b_w1, const float* __restrict__ b_b1,
    const float* __restrict__ b_g,  const float* __restrict__ b_beta,
    const float* __restrict__ b_w2, const float* __restrict__ b_b2,
    unsigned short* __restrict__ wbf,  // [B][CH_out][CH_in] bf16 bits
    float* __restrict__ bias)          // [B][CH]
{
  const int blk = blockIdx.x;
  const int b   = blk >> 2;
  const int qt  = blk & 3;          // 1024-entry quarter of the weight head
  const int tid = threadIdx.x;

  __shared__ float zs[INS];
  __shared__ float hraw[2][HID];
  __shared__ float hn[2][HID];

  if (tid < INS) zs[tid] = z[b * INS + tid];
  __syncthreads();

  if (tid < 2 * HID) {
    const int grp = tid >> 5;          // 0 = weight-MLP, 1 = bias-MLP
    const int j   = tid & 31;
    const float* w1 = grp ? b_w1 : w_w1;
    const float* b1 = grp ? b_b1 : w_b1;
    hraw[grp][j] = w1[j*3+0]*zs[0] + w1[j*3+1]*zs[1] + w1[j*3+2]*zs[2] + b1[j];
  }
  __syncthreads();

  if (tid < 2 * HID) {
    const int grp = tid >> 5;
    const int j   = tid & 31;
    float mu = 0.f;
    #pragma unroll
    for (int k = 0; k < HID; ++k) mu += hraw[grp][k];
    mu *= (1.0f / HID);
    float var = 0.f;
    #pragma unroll
    for (int k = 0; k < HID; ++k) { float d = hraw[grp][k] - mu; var += d * d; }
    var *= (1.0f / HID);
    const float r  = rsqrtf(var + 1e-5f);
    const float* g  = grp ? b_g    : w_g;
    const float* be = grp ? b_beta : w_beta;
    const float v = (hraw[grp][j] - mu) * r * g[j] + be[j];
    hn[grp][j] = fmaxf(v, 0.f);
  }
  __syncthreads();

  float h0[HID];
  #pragma unroll
  for (int j = 0; j < HID; ++j) h0[j] = hn[0][j];

  #pragma unroll
  for (int e = 0; e < 4; ++e) {
    const int m = qt * 1024 + e * 256 + tid;
    const float4* row = (const float4*)(w_w2 + (size_t)m * HID);
    float acc = w_b2[m];
    #pragma unroll
    for (int qq = 0; qq < 8; ++qq) {
      const float4 v = row[qq];
      acc += h0[qq*4+0] * v.x + h0[qq*4+1] * v.y
           + h0[qq*4+2] * v.z + h0[qq*4+3] * v.w;
    }
    wbf[(size_t)b * CH * CH + m] = f2bf_bits(acc);
  }

  if (qt == 0 && tid < CH) {
    const float4* row = (const float4*)(b_w2 + (size_t)tid * HID);
    float acc = b_b2[tid];
    #pragma unroll
    for (int qq = 0; qq < 8; ++qq) {
      const float4 v = row[qq];
      acc += hn[1][qq*4+0] * v.x + hn[1][qq*4+1] * v.y
           + hn[1][qq*4+2] * v.z + hn[1][qq*4+3] * v.w;
    }
    bias[b * CH + tid] = acc;
  }
}

// ---------------------------------------------------------------------------
// Kernel 2 round-21: 128-t tile, 4 blocks/CU (34.3 KB LDS), keeping r20's
// copy-shaped accesses. Staging inst = one k-row-PAIR x 1024 B contiguous
// (per-lane global addr: lanes 0-31 -> row 2m, 32-63 -> row 2m+1; LDS dest
// linear). Pair-pitch 268 floats: 16B-aligned insts, and (k>>1)*268 spreads
// g-groups 2-way across banks -> compute ds_reads conflict-free.
// After compute, transpose overlay reuses the (dead) staging LDS; store
// sweep = one NT inst per o-pair x 1024 B contiguous. 4 resident blocks/CU
// double the cross-block phase overlap vs r20's 2 (the residual ~25% gap:
// neither read nor write stream saturated, compute idle -> phase serialization).
// lds(k,t) = (k>>1)*268 + (k&1)*128 + t.
// ---------------------------------------------------------------------------
#define WAITB(N)                                                              \
  {                                                                           \
    asm volatile("s_waitcnt vmcnt(" #N ")" ::: "memory");                     \
    __builtin_amdgcn_s_barrier();                                             \
    asm volatile("" ::: "memory");                                            \
  }

#define LGKMB                                                                 \
  {                                                                           \
    asm volatile("s_waitcnt lgkmcnt(0)" ::: "memory");                        \
    __builtin_amdgcn_s_barrier();                                             \
    asm volatile("" ::: "memory");                                            \
  }

__global__ __launch_bounds__(256, 4) void conv1x1_mfma(
    const float* __restrict__ x,
    const unsigned short* __restrict__ wbf,
    const float* __restrict__ bias,
    float* __restrict__ out)
{
  __shared__ __align__(16) float lds[32 * PPITCH];   // 34304 B -> 4 blocks/CU

  const int b    = blockIdx.y;
  const int tbi  = blockIdx.x;      // 128-t tile (0..31)
  const int tid  = threadIdx.x;
  const int lane = tid & 63;
  const int wid  = tid >> 6;        // 0..3 (uniform per wave)
  const int g    = lane >> 4;       // 16-lane group
  const int r    = lane & 15;

  // A-frags: wbf[b][ot*16 + r][ks*32 + g*8 + 0..7]  (8 x 16B loads)
  const unsigned short* wb = wbf + (size_t)b * CH * CH;
  short8 afrag[4][2];
  #pragma unroll
  for (int ot = 0; ot < 4; ++ot)
    #pragma unroll
    for (int ks = 0; ks < 2; ++ks)
      afrag[ot][ks] = *(const short8*)(wb + (ot * 16 + r) * CH + ks * 32 + g * 8);

  // bias for lane's output rows o = ot*16 + g*4 + q  (4 x 16B loads)
  float bv[4][4];
  #pragma unroll
  for (int ot = 0; ot < 4; ++ot) {
    const float4 t = *(const float4*)(bias + b * CH + ot * 16 + g * 4);
    bv[ot][0] = t.x; bv[ot][1] = t.y; bv[ot][2] = t.z; bv[ot][3] = t.w;
  }

  const float* xb = x   + (size_t)b * CH * T_LEN + tbi * 128;
  float*       ob = out + (size_t)b * CH * T_LEN + tbi * 128;

  // accumulators [nt][ot], bias-initialized (nt = 0,1: t-range wid*32+nt*16)
  f32x4 acc[2][4];
  #pragma unroll
  for (int nt = 0; nt < 2; ++nt)
    #pragma unroll
    for (int ot = 0; ot < 4; ++ot) {
      f32x4 a = {bv[ot][0], bv[ot][1], bv[ot][2], bv[ot][3]};
      acc[nt][ot] = a;
    }

  // ---- stage: 8 insts/wave; inst m covers rows {2m, 2m+1} x 128 t x 4B ----
  #pragma unroll
  for (int q = 0; q < 8; ++q) {
    const int m = wid * 8 + q;      // row pair 0..31
    const float* ga = xb + (size_t)(2 * m + (lane >> 5)) * T_LEN + (lane & 31) * 4;
    __builtin_amdgcn_global_load_lds((gfloat1*)ga,
        (sfloat3*)(lds + m * PPITCH), 16, 0, 0);
  }

  WAITB(0)          // all 64 rows resident

  // ---- compute: k = ks*32 + g*8 + j, t = wid*32 + nt*16 + r ----
  #pragma unroll
  for (int ks = 0; ks < 2; ++ks) {
    #pragma unroll
    for (int nt = 0; nt < 2; ++nt) {
      union { short8 s; unsigned short u[8]; } bfv;
      #pragma unroll
      for (int j = 0; j < 8; ++j) {
        const float f = lds[(ks * 16 + g * 4 + (j >> 1)) * PPITCH
                            + (j & 1) * 128 + wid * 32 + nt * 16 + r];
        bfv.u[j] = f2bf_bits(f);
      }
      acc[nt][0] = __builtin_amdgcn_mfma_f32_16x16x32_bf16(afrag[0][ks], bfv.s, acc[nt][0], 0, 0, 0);
      acc[nt][1] = __builtin_amdgcn_mfma_f32_16x16x32_bf16(afrag[1][ks], bfv.s, acc[nt][1], 0, 0, 0);
      acc[nt][2] = __builtin_amdgcn_mfma_f32_16x16x32_bf16(afrag[2][ks], bfv.s, acc[nt][2], 0, 0, 0);
      acc[nt][3] = __builtin_amdgcn_mfma_f32_16x16x32_bf16(afrag[3][ks], bfv.s, acc[nt][3], 0, 0, 0);
    }
  }

  // ---- transpose overlay into dead staging LDS ----
  LGKMB             // all ds_reads retired -> safe to overwrite

  // xp(o,t) at (o>>1)*PPITCH + (o&1)*128 + t; o = ot*16 + g*4 + qq
  #pragma unroll
  for (int nt = 0; nt < 2; ++nt)
    #pragma unroll
    for (int ot = 0; ot < 4; ++ot)
      #pragma unroll
      for (int qq = 0; qq < 4; ++qq)
        lds[(ot * 8 + g * 2 + (qq >> 1)) * PPITCH + (qq & 1) * 128
            + wid * 32 + nt * 16 + r] = acc[nt][ot][qq];

  LGKMB             // xp visible to all waves

  // ---- NT store sweep: inst p covers o-pair {2p, 2p+1} x 512 B each ----
  #pragma unroll
  for (int s = 0; s < 8; ++s) {
    const int p = wid * 8 + s;      // o-pair 0..31
    const f32x4 v = *(const f32x4*)(&lds[p * PPITCH + (lane >> 5) * 128 + (lane & 31) * 4]);
    __builtin_nontemporal_store(v,
        (f32x4*)(&ob[(size_t)(2 * p + (lane >> 5)) * T_LEN + (lane & 31) * 4]));
  }
}

extern "C" void kernel_launch(void* const* d_in, const int* in_sizes, int n_in,
                              void* d_out, int out_size, void* d_ws, size_t ws_size,
                              hipStream_t stream) {
  const float* x      = (const float*)d_in[0];
  const float* z      = (const float*)d_in[1];
  const float* w_w1   = (const float*)d_in[2];
  const float* w_b1   = (const float*)d_in[3];
  const float* w_g    = (const float*)d_in[4];
  const float* w_beta = (const float*)d_in[5];
  const float* w_w2   = (const float*)d_in[6];
  const float* w_b2   = (const float*)d_in[7];
  const float* b_w1   = (const float*)d_in[8];
  const float* b_b1   = (const float*)d_in[9];
  const float* b_g    = (const float*)d_in[10];
  const float* b_beta = (const float*)d_in[11];
  const float* b_w2   = (const float*)d_in[12];
  const float* b_b2   = (const float*)d_in[13];

  float* out = (float*)d_out;
  unsigned short* wbf = (unsigned short*)d_ws;                 // 128*4096 bf16 = 1 MB
  float* bias = (float*)((char*)d_ws + (size_t)B_SZ * CH * CH * sizeof(unsigned short));

  hyper_mlp_kernel<<<B_SZ * 4, 256, 0, stream>>>(
      z, w_w1, w_b1, w_g, w_beta, w_w2, w_b2,
      b_w1, b_b1, b_g, b_beta, b_w2, b_b2, wbf, bias);

  dim3 grid(T_LEN / 128, B_SZ);
  conv1x1_mfma<<<grid, 256, 0, stream>>>(x, wbf, bias, out);
}